// Round 9
// baseline (556.702 us; speedup 1.0000x reference)
//
#include <hip/hip_runtime.h>
#include <hip/hip_bf16.h>

// VectorQuantizer B=32768, K=4096, D=512, fp32 in/out.
// Out concat (f32): quantized_st[B*512] | indices[B] | loss | perplexity | encodings[B*4096].
// R9: strip-batched exchange. 4 cf (64 cols) processed barrier-free; both K-half
// partials shipped to a 32KB LDS buffer; ONE barrier -> batched epilogue -> ONE
// barrier. Barriers 128->64, loads pipeline across cf. Screen math identical to
// R8; numpy-fp32 rescore + npsum verbatim (validated R5-R8).

typedef __attribute__((ext_vector_type(8))) short bf16x8;
typedef __attribute__((ext_vector_type(4))) float f32x4;

#define BB 32768
#define KK 4096
#define DD 512

#define IDX_OFF  (BB*DD)
#define LOSS_OFF (IDX_OFF + BB)
#define PERP_OFF (LOSS_OFF + 1)
#define ENC_OFF  (PERP_OFF + 1)

// ws byte offsets
#define WSB_XSQ  0
#define WSB_ESQ  131072
#define WSB_IDX  147456
#define WSB_HIST 278528
#define WSB_LOSS 294912
#define WSB_EBF  294928        // 4 MB bf16 codebook, fragment-packed

#define MARG 2.5e-4f
#define NCAND 24

static __device__ __forceinline__ unsigned short f2bf(float f) {
    __hip_bfloat16 h = __float2bfloat16(f);
    return *reinterpret_cast<unsigned short*>(&h);
}

// monotone-packed score: high 20 bits order-preserving float, low 12 col
static __device__ __forceinline__ unsigned int packscore(float s, int col) {
    unsigned int u = __float_as_uint(s);
    u ^= (u & 0x80000000u) ? 0xFFFFFFFFu : 0x80000000u;
    return (u & 0xFFFFF000u) | (unsigned int)col;
}
static __device__ __forceinline__ float unpackscore(unsigned int p) {
    unsigned int u = p & 0xFFFFF000u;
    u = (u & 0x80000000u) ? (u ^ 0x80000000u) : ~u;
    return __uint_as_float(u);
}

__global__ __launch_bounds__(256) void init_kernel(int* __restrict__ hist,
                                                   double* __restrict__ loss_acc) {
    int i = blockIdx.x * 256 + threadIdx.x;
    if (i < KK) hist[i] = 0;
    if (i == 0) *loss_acc = 0.0;
}

// numpy-emulated row sum-of-squares (pairwise-128 + AVX512 lane fold) — validated R5-R8
__global__ __launch_bounds__(256) void npsum_kernel(const float* __restrict__ X,
                                                    const float* __restrict__ E,
                                                    float* __restrict__ xsq,
                                                    float* __restrict__ esq) {
    __shared__ float sq[4][512];
    __shared__ float ub[4][64];
    __shared__ float bb[4][4];
    int w = threadIdx.x >> 6, lane = threadIdx.x & 63;
    int row = blockIdx.x * 4 + w;
    const float* src; float* dst;
    if (row < BB) { src = X + (size_t)row * DD;        dst = xsq + row; }
    else          { src = E + (size_t)(row - BB) * DD; dst = esq + (row - BB); }
    #pragma unroll
    for (int m = 0; m < 8; ++m) {
        float v = src[m * 64 + lane];
        sq[w][m * 64 + lane] = __fmul_rn(v, v);
    }
    __syncthreads();
    {
        int b = lane >> 4, l = lane & 15;
        const float* s = &sq[w][b * 128];
        float t = __fadd_rn(
            __fadd_rn(__fadd_rn(s[l], s[16 + l]), __fadd_rn(s[32 + l], s[48 + l])),
            __fadd_rn(__fadd_rn(s[64 + l], s[80 + l]), __fadd_rn(s[96 + l], s[112 + l])));
        ub[w][lane] = t;
    }
    __syncthreads();
    if (lane < 4) {
        const float* u = &ub[w][lane * 16];
        float T3[8], T6[4];
        #pragma unroll
        for (int i = 0; i < 8; ++i) T3[i] = __fadd_rn(u[i], u[i + 8]);
        #pragma unroll
        for (int i = 0; i < 4; ++i) T6[i] = __fadd_rn(T3[i], T3[i + 4]);
        bb[w][lane] = __fadd_rn(__fadd_rn(T6[0], T6[2]), __fadd_rn(T6[1], T6[3]));
    }
    __syncthreads();
    if (lane == 0)
        *dst = __fadd_rn(__fadd_rn(bb[w][0], bb[w][1]), __fadd_rn(bb[w][2], bb[w][3]));
}

// codebook fp32 -> bf16, FRAGMENT-PACKED: bf16x8 index ((cf*16+ks)*64 + lane)
// holds E[cf*16 + (lane&15)][ks*32 + (lane>>4)*8 + 0..7].
__global__ __launch_bounds__(256) void ecvt_kernel(const float* __restrict__ E,
                                                   unsigned short* __restrict__ Ebf) {
    int t = blockIdx.x * 256 + threadIdx.x;     // 262144 threads
    int lane = t & 63, rest = t >> 6;
    int ks = rest & 15, cf = rest >> 4;
    int c = lane & 15, g = lane >> 4;
    const float* src = E + (size_t)(cf * 16 + c) * DD + ks * 32 + g * 8;
    float4 a = ((const float4*)src)[0], b = ((const float4*)src)[1];
    union { bf16x8 v; unsigned short u[8]; } pk;
    pk.u[0] = f2bf(a.x); pk.u[1] = f2bf(a.y); pk.u[2] = f2bf(a.z); pk.u[3] = f2bf(a.w);
    pk.u[4] = f2bf(b.x); pk.u[5] = f2bf(b.y); pk.u[6] = f2bf(b.z); pk.u[7] = f2bf(b.w);
    *(bf16x8*)(Ebf + (size_t)t * 8) = pk.v;
}

// main: K-split bf16 MFMA screen with strip-batched exchange.
// 256 thr = 4 waves; wave w: kw=w>>1 (K-half), cw=w&1 (col-half). Rows/block 32.
__global__ __launch_bounds__(256, 4) void vq_mfma(
    const float* __restrict__ X, const float* __restrict__ E,
    const unsigned short* __restrict__ Ebf,
    const float* __restrict__ xsqw, const float* __restrict__ esqw,
    int* __restrict__ idxbuf, int* __restrict__ hist,
    double* __restrict__ loss_acc, float* __restrict__ out)
{
    __shared__ __align__(16) char pool[32768];
    // K-loop view: xch[cfl4][rf][kw_writer][cw][lane] : f32x4  (32 KB)
    f32x4 (*xch)[2][2][2][64] = (f32x4 (*)[2][2][2][64])pool;
    // post-loop aliases:
    unsigned int (*P1)[16] = (unsigned int (*)[16])pool;            // [32][16]
    unsigned int (*P2)[16] = (unsigned int (*)[16])(pool + 4096);   // [32][16]
    int*    sidx = (int*)(pool + 8192);
    double* lsr  = (double*)(pool + 8448);

    const int tid  = threadIdx.x;
    const int w    = tid >> 6;
    const int kw   = w >> 1;        // K-half: k in [kw*256, kw*256+256)
    const int cw   = w & 1;         // col-half: cf in [cw*128, cw*128+128)
    const int lane = tid & 63;
    const int c    = lane & 15;
    const int g    = lane >> 4;
    const int row0 = blockIdx.x * 32;

    // A fragments for this wave's K-half: rows rf*16+c
    bf16x8 afrag[2][8];
    #pragma unroll
    for (int rf = 0; rf < 2; ++rf) {
        const float* xrow = X + (size_t)(row0 + rf * 16 + c) * DD + kw * 256;
        #pragma unroll
        for (int ks = 0; ks < 8; ++ks) {
            const float4* s = (const float4*)(xrow + ks * 32 + g * 8);
            float4 a = s[0], b = s[1];
            union { bf16x8 v; unsigned short u[8]; } pk;
            pk.u[0] = f2bf(a.x); pk.u[1] = f2bf(a.y);
            pk.u[2] = f2bf(a.z); pk.u[3] = f2bf(a.w);
            pk.u[4] = f2bf(b.x); pk.u[5] = f2bf(b.y);
            pk.u[6] = f2bf(b.z); pk.u[7] = f2bf(b.w);
            afrag[rf][ks] = pk.v;
        }
    }

    unsigned int p1[4], p2[4];
    #pragma unroll
    for (int r = 0; r < 4; ++r) { p1[r] = 0xFFFFFFFFu; p2[r] = 0xFFFFFFFFu; }

    for (int st = 0; st < 32; ++st) {
        // ---- 4 cf, barrier-free: loads pipeline across cf ----
        #pragma unroll
        for (int cfl4 = 0; cfl4 < 4; ++cfl4) {
            const int cf = cw * 128 + st * 4 + cfl4;
            const bf16x8* bsrc = (const bf16x8*)Ebf + ((size_t)(cf * 16 + kw * 8)) * 64 + lane;
            f32x4 acc0 = (f32x4){0.f, 0.f, 0.f, 0.f};
            f32x4 acc1 = (f32x4){0.f, 0.f, 0.f, 0.f};
            #pragma unroll
            for (int ks = 0; ks < 8; ++ks) {
                bf16x8 b = bsrc[ks * 64];
                acc0 = __builtin_amdgcn_mfma_f32_16x16x32_bf16(afrag[0][ks], b, acc0, 0, 0, 0);
                acc1 = __builtin_amdgcn_mfma_f32_16x16x32_bf16(afrag[1][ks], b, acc1, 0, 0, 0);
            }
            xch[cfl4][0][kw][cw][lane] = acc0;
            xch[cfl4][1][kw][cw][lane] = acc1;
        }
        __syncthreads();
        // ---- batched epilogue: wave (kw,cw) finalizes rf=kw rows ----
        #pragma unroll
        for (int cfl4 = 0; cfl4 < 4; ++cfl4) {
            const int cf = cw * 128 + st * 4 + cfl4;
            f32x4 pa = xch[cfl4][kw][0][cw][lane];
            f32x4 pb = xch[cfl4][kw][1][cw][lane];
            const int col = cf * 16 + c;
            const float esqc = esqw[col];
            #pragma unroll
            for (int r = 0; r < 4; ++r) {
                float s = fmaf(-2.0f, __fadd_rn(pa[r], pb[r]), esqc);
                unsigned int q = packscore(s, col);
                if (q < p1[r]) { p2[r] = p1[r]; p1[r] = q; }
                else if (q < p2[r]) p2[r] = q;
            }
        }
        __syncthreads();
    }

    // merge: wave (kw,cw) owns rows kw*16 + g*4 + r, col-slot c
    #pragma unroll
    for (int r = 0; r < 4; ++r) {
        int row = kw * 16 + g * 4 + r;
        P1[cw * 32 + row][c] = p1[r];   // P1 viewed as [2][32][16] flattened
        P2[cw * 32 + row][c] = p2[r];
    }
    __syncthreads();

    if (tid < 32) {
        const int row = tid;
        unsigned int m = 0xFFFFFFFFu;
        #pragma unroll
        for (int ww = 0; ww < 2; ++ww)
            for (int t = 0; t < 16; ++t) m = min(m, P1[ww * 32 + row][t]);
        float lim = unpackscore(m) + MARG;
        int cand[NCAND]; int nc = 0;
        for (int ww = 0; ww < 2; ++ww)
            for (int t = 0; t < 16; ++t) {
                unsigned int a1 = P1[ww * 32 + row][t], a2 = P2[ww * 32 + row][t];
                if (unpackscore(a1) <= lim && nc < NCAND) cand[nc++] = (int)(a1 & 0xFFFu);
                if (unpackscore(a2) <= lim && nc < NCAND) cand[nc++] = (int)(a2 & 0xFFFu);
            }
        // numpy-fp32 emulated rescore (verbatim, validated R5-R8)
        const float* xr = X + (size_t)(row0 + row) * DD;
        float xs = xsqw[row0 + row];
        float bd = 3.0e38f; int bk = 0x7fffffff;
        for (int cidx = 0; cidx < nc; ++cidx) {
            int k = cand[cidx] & (KK - 1);
            const float* er = E + (size_t)k * DD;
            float q1 = 0.f, q2 = 0.f;
            for (int d = 0; d < 384; ++d)   q1 = fmaf(xr[d], er[d], q1);
            for (int d = 384; d < 512; ++d) q2 = fmaf(xr[d], er[d], q2);
            float dot = __fadd_rn(q1, q2);
            float t1  = __fadd_rn(xs, esqw[k]);
            float dnp = __fsub_rn(t1, __fmul_rn(2.0f, dot));
            if (dnp < bd || (dnp == bd && k < bk)) { bd = dnp; bk = k; }
        }
        const float* er = E + (size_t)bk * DD;
        double ls = 0.0;
        for (int d = 0; d < DD; ++d) {
            double df = (double)xr[d] - (double)er[d];
            ls = fma(df, df, ls);
        }
        lsr[row] = ls;
        sidx[row] = bk;
        idxbuf[row0 + row] = bk;
        out[IDX_OFF + row0 + row] = (float)bk;
        atomicAdd(&hist[bk], 1);
    }
    __syncthreads();
    // quantized_st = codebook gather, fp32
    for (int e = tid; e < 32 * DD / 4; e += 256) {
        int r = e >> 7, d = (e & 127) * 4;
        int ci = sidx[r];
        float4 q4 = *(const float4*)&E[(size_t)ci * DD + d];
        *(float4*)&out[(size_t)(row0 + r) * DD + d] = q4;
    }
    if (tid == 0) {
        double s = 0.0;
        #pragma unroll 8
        for (int i = 0; i < 32; ++i) s += lsr[i];
        atomicAdd(loss_acc, s);
    }
}

__global__ __launch_bounds__(256) void enc_kernel(const int* __restrict__ idxbuf,
                                                  float* __restrict__ out) {
    int row = blockIdx.x;
    int idx = idxbuf[row];
    float2* erow = (float2*)(out + ENC_OFF) + (size_t)row * (KK / 2);
    int half = idx >> 1;
    float2 one;
    if (idx & 1) { one.x = 0.f; one.y = 1.f; } else { one.x = 1.f; one.y = 0.f; }
    float2 z; z.x = 0.f; z.y = 0.f;
    for (int c = threadIdx.x; c < KK / 2; c += 256)
        erow[c] = (c == half) ? one : z;
}

__global__ __launch_bounds__(256) void fin_kernel(const int* __restrict__ hist,
                                                  const double* __restrict__ loss_acc,
                                                  float* __restrict__ out) {
    __shared__ double red[256];
    int tid = threadIdx.x;
    double s = 0.0;
    for (int k = tid; k < KK; k += 256) {
        double p = (double)hist[k] * (1.0 / 32768.0);
        s += p * log(p + 1e-10);
    }
    red[tid] = s;
    __syncthreads();
    for (int t = 128; t > 0; t >>= 1) {
        if (tid < t) red[tid] += red[tid + t];
        __syncthreads();
    }
    if (tid == 0) {
        double perp = exp(-red[0]);
        double L = loss_acc[0] * (1.0 / ((double)BB * (double)DD));
        out[LOSS_OFF] = (float)(1.25 * L);
        out[PERP_OFF] = (float)perp;
    }
}

extern "C" void kernel_launch(void* const* d_in, const int* in_sizes, int n_in,
                              void* d_out, int out_size, void* d_ws, size_t ws_size,
                              hipStream_t stream) {
    const float* X; const float* E;
    if (in_sizes[0] == BB * DD) { X = (const float*)d_in[0]; E = (const float*)d_in[1]; }
    else                        { X = (const float*)d_in[1]; E = (const float*)d_in[0]; }
    float* out = (float*)d_out;

    float* xsq = (float*)((char*)d_ws + WSB_XSQ);
    float* esq = (float*)((char*)d_ws + WSB_ESQ);
    int* idxbuf = (int*)((char*)d_ws + WSB_IDX);
    int* hist   = (int*)((char*)d_ws + WSB_HIST);
    double* loss_acc = (double*)((char*)d_ws + WSB_LOSS);
    unsigned short* Ebf = (unsigned short*)((char*)d_ws + WSB_EBF);

    hipLaunchKernelGGL(init_kernel, dim3(16), dim3(256), 0, stream, hist, loss_acc);
    hipLaunchKernelGGL(npsum_kernel, dim3((BB + KK) / 4), dim3(256), 0, stream,
                       X, E, xsq, esq);
    hipLaunchKernelGGL(ecvt_kernel, dim3(1024), dim3(256), 0, stream, E, Ebf);
    hipLaunchKernelGGL(vq_mfma, dim3(BB / 32), dim3(256), 0, stream,
                       X, E, Ebf, xsq, esq, idxbuf, hist, loss_acc, out);
    hipLaunchKernelGGL(enc_kernel, dim3(BB), dim3(256), 0, stream, idxbuf, out);
    hipLaunchKernelGGL(fin_kernel, dim3(1), dim3(256), 0, stream, hist, loss_acc, out);
}

// Round 11
// 477.169 us; speedup vs baseline: 1.1667x; 1.1667x over previous
//
#include <hip/hip_runtime.h>
#include <hip/hip_bf16.h>

// VectorQuantizer B=32768, K=4096, D=512, fp32 in/out.
// Out concat (f32): quantized_st[B*512] | indices[B] | loss | perplexity | encodings[B*4096].
// R11: m97-style GEMM screen, BOTH operands via global_load_lds from
// fragment-packed bf16 buffers (Xbf 32MB, Ebf2 4MB in ws). 128x128 tile, BK=64,
// dbuf LDS, 1 barrier/K-step. Fixes R10 compile (no LDS pointer arrays) and VGPR
// pressure (no reg-staging). Top-2 partials -> reduce with numpy-fp32 rescore
// (verbatim, validated R5-R9). XCD-bijective swizzle.

typedef __attribute__((ext_vector_type(8))) short bf16x8;
typedef __attribute__((ext_vector_type(4))) float f32x4;

#define BB 32768
#define KK 4096
#define DD 512

#define IDX_OFF  (BB*DD)
#define LOSS_OFF (IDX_OFF + BB)
#define PERP_OFF (LOSS_OFF + 1)
#define ENC_OFF  (PERP_OFF + 1)

// ws byte offsets
#define WSB_XSQ  0
#define WSB_ESQ  131072
#define WSB_IDX  147456
#define WSB_HIST 278528
#define WSB_LOSS 294912
#define WSB_EBF2 294928          // 4 MB: E bf16, fragment-packed per (cb,kt) 16KB chunk
#define WSB_XBF  4489232         // 32 MB: X bf16, fragment-packed per (rb,kt) 16KB chunk
#define WSB_PART 38043664        // 16 MB: uint2 partials [64][32768]

#define MARG 2.5e-4f
#define NCAND 16

static __device__ __forceinline__ unsigned short f2bf(float f) {
    __hip_bfloat16 h = __float2bfloat16(f);
    return *reinterpret_cast<unsigned short*>(&h);
}

static __device__ __forceinline__ unsigned int packscore(float s, int col) {
    unsigned int u = __float_as_uint(s);
    u ^= (u & 0x80000000u) ? 0xFFFFFFFFu : 0x80000000u;
    return (u & 0xFFFFF000u) | (unsigned int)col;
}
static __device__ __forceinline__ float unpackscore(unsigned int p) {
    unsigned int u = p & 0xFFFFF000u;
    u = (u & 0x80000000u) ? (u ^ 0x80000000u) : ~u;
    return __uint_as_float(u);
}

static __device__ __forceinline__ void gll16(const void* g, void* l) {
    __builtin_amdgcn_global_load_lds(
        (const __attribute__((address_space(1))) unsigned int*)g,
        (__attribute__((address_space(3))) unsigned int*)l, 16, 0, 0);
}

__global__ __launch_bounds__(256) void init_kernel(int* __restrict__ hist,
                                                   double* __restrict__ loss_acc) {
    int i = blockIdx.x * 256 + threadIdx.x;
    if (i < KK) hist[i] = 0;
    if (i == 0) *loss_acc = 0.0;
}

// numpy-emulated row sum-of-squares (pairwise-128 + AVX512 lane fold) — validated R5-R9
__global__ __launch_bounds__(256) void npsum_kernel(const float* __restrict__ X,
                                                    const float* __restrict__ E,
                                                    float* __restrict__ xsq,
                                                    float* __restrict__ esq) {
    __shared__ float sq[4][512];
    __shared__ float ub[4][64];
    __shared__ float bb[4][4];
    int w = threadIdx.x >> 6, lane = threadIdx.x & 63;
    int row = blockIdx.x * 4 + w;
    const float* src; float* dst;
    if (row < BB) { src = X + (size_t)row * DD;        dst = xsq + row; }
    else          { src = E + (size_t)(row - BB) * DD; dst = esq + (row - BB); }
    #pragma unroll
    for (int m = 0; m < 8; ++m) {
        float v = src[m * 64 + lane];
        sq[w][m * 64 + lane] = __fmul_rn(v, v);
    }
    __syncthreads();
    {
        int b = lane >> 4, l = lane & 15;
        const float* s = &sq[w][b * 128];
        float t = __fadd_rn(
            __fadd_rn(__fadd_rn(s[l], s[16 + l]), __fadd_rn(s[32 + l], s[48 + l])),
            __fadd_rn(__fadd_rn(s[64 + l], s[80 + l]), __fadd_rn(s[96 + l], s[112 + l])));
        ub[w][lane] = t;
    }
    __syncthreads();
    if (lane < 4) {
        const float* u = &ub[w][lane * 16];
        float T3[8], T6[4];
        #pragma unroll
        for (int i = 0; i < 8; ++i) T3[i] = __fadd_rn(u[i], u[i + 8]);
        #pragma unroll
        for (int i = 0; i < 4; ++i) T6[i] = __fadd_rn(T3[i], T3[i + 4]);
        bb[w][lane] = __fadd_rn(__fadd_rn(T6[0], T6[2]), __fadd_rn(T6[1], T6[3]));
    }
    __syncthreads();
    if (lane == 0)
        *dst = __fadd_rn(__fadd_rn(bb[w][0], bb[w][1]), __fadd_rn(bb[w][2], bb[w][3]));
}

// fp32 row-major [rows][512] -> bf16 fragment-packed 16KB chunks.
// unit t: chunk = t>>10 = rb*8+kt, u = t&1023 = (nf*2+ks)*64+lane;
// holds src[rb*128+nf*16+(lane&15)][kt*64+ks*32+(lane>>4)*8 .. +7]
__global__ __launch_bounds__(256) void pack_kernel(const float* __restrict__ src,
                                                   unsigned short* __restrict__ dst) {
    int t = blockIdx.x * 256 + threadIdx.x;
    int chunk = t >> 10, u = t & 1023;
    int rb = chunk >> 3, kt = chunk & 7;
    int nf = u >> 7, ks = (u >> 6) & 1, lane = u & 63;
    int row = rb * 128 + nf * 16 + (lane & 15);
    int k   = kt * 64 + ks * 32 + (lane >> 4) * 8;
    const float4* s = (const float4*)(src + (size_t)row * DD + k);
    float4 a = s[0], b = s[1];
    union { bf16x8 v; unsigned short us[8]; } pk;
    pk.us[0] = f2bf(a.x); pk.us[1] = f2bf(a.y); pk.us[2] = f2bf(a.z); pk.us[3] = f2bf(a.w);
    pk.us[4] = f2bf(b.x); pk.us[5] = f2bf(b.y); pk.us[6] = f2bf(b.z); pk.us[7] = f2bf(b.w);
    *(bf16x8*)(dst + (size_t)t * 8) = pk.v;
}

// GEMM screen: grid 8192 = 256 rb x 32 cb (XCD-swizzled), 256 thr (4 waves).
__global__ __launch_bounds__(256, 2) void gemm_screen(
    const unsigned short* __restrict__ Xbf, const unsigned short* __restrict__ Ebf2,
    const float* __restrict__ esqw, uint2* __restrict__ partials)
{
    __shared__ __align__(16) char pool[65536];

    const int tid = threadIdx.x;
    const int w = tid >> 6, lane = tid & 63;
    const int c = lane & 15, g = lane >> 4;
    const int bid = blockIdx.x;
    const int orig = (bid & 7) * 1024 + (bid >> 3);   // bijective: 8192 % 8 == 0
    const int rb = orig >> 5, cb = orig & 31;
    const int row0 = rb * 128, col0 = cb * 128;
    const int mw = w >> 1, nw = w & 1;

    const char* Xc = (const char*)Xbf  + (size_t)rb * 8 * 16384;
    const char* Ec = (const char*)Ebf2 + (size_t)cb * 8 * 16384;

    f32x4 acc[4][4];
    #pragma unroll
    for (int i = 0; i < 4; ++i)
        #pragma unroll
        for (int j = 0; j < 4; ++j) acc[i][j] = (f32x4){0.f, 0.f, 0.f, 0.f};

    // gll16: LDS dest = wave-uniform base + lane*16; src per-lane. Chunk unit u
    // lands at LDS unit u (dest base + it*4096 + w*1024, src + it*4096 + tid*16).
    #define STAGE(srcc_, kt_, dstoff_) { \
        const char* s_ = (srcc_) + (size_t)(kt_) * 16384 + (size_t)tid * 16; \
        char* d_ = pool + (dstoff_) + w * 1024; \
        gll16(s_,         d_); \
        gll16(s_ + 4096,  d_ + 4096); \
        gll16(s_ + 8192,  d_ + 8192); \
        gll16(s_ + 12288, d_ + 12288); }

    STAGE(Xc, 0, 0); STAGE(Ec, 0, 32768);
    __syncthreads();
    int buf = 0;
    for (int kt = 0; kt < 8; ++kt) {
        if (kt < 7) {
            STAGE(Xc, kt + 1, (buf ^ 1) * 16384);
            STAGE(Ec, kt + 1, 32768 + (buf ^ 1) * 16384);
        }
        const char* Ap = pool + buf * 16384;
        const char* Bp = pool + 32768 + buf * 16384;
        #pragma unroll
        for (int ks = 0; ks < 2; ++ks) {
            bf16x8 af[4], bfr[4];
            #pragma unroll
            for (int i = 0; i < 4; ++i) {
                af[i]  = *(const bf16x8*)(Ap + ((((mw * 4 + i) * 2 + ks) * 64) + lane) * 16);
                bfr[i] = *(const bf16x8*)(Bp + ((((nw * 4 + i) * 2 + ks) * 64) + lane) * 16);
            }
            #pragma unroll
            for (int mf = 0; mf < 4; ++mf)
                #pragma unroll
                for (int nf = 0; nf < 4; ++nf)
                    acc[mf][nf] = __builtin_amdgcn_mfma_f32_16x16x32_bf16(af[mf], bfr[nf], acc[mf][nf], 0, 0, 0);
        }
        __syncthreads();
        buf ^= 1;
    }

    // epilogue: scores -> per-lane top2-of-4nf -> LDS -> per-(row,nw) top2 -> partials
    uint2* P = (uint2*)pool;   // [2][128][16] = 32 KB
    #pragma unroll
    for (int mf = 0; mf < 4; ++mf) {
        #pragma unroll
        for (int r = 0; r < 4; ++r) {
            unsigned int q1 = 0xFFFFFFFFu, q2 = 0xFFFFFFFFu;
            int rowl = mw * 64 + mf * 16 + g * 4 + r;
            #pragma unroll
            for (int nf = 0; nf < 4; ++nf) {
                int col = col0 + nw * 64 + nf * 16 + c;
                float s = fmaf(-2.0f, acc[mf][nf][r], esqw[col]);
                unsigned int q = packscore(s, col);
                if (q < q1) { q2 = q1; q1 = q; } else if (q < q2) q2 = q;
            }
            P[(nw * 128 + rowl) * 16 + c] = make_uint2(q1, q2);
        }
    }
    __syncthreads();
    if (tid < 128) {
        int row = tid;
        #pragma unroll
        for (int n2 = 0; n2 < 2; ++n2) {
            unsigned int m1 = 0xFFFFFFFFu, m2 = 0xFFFFFFFFu;
            #pragma unroll 4
            for (int cc = 0; cc < 16; ++cc) {
                uint2 e = P[(n2 * 128 + row) * 16 + cc];
                if (e.x < m1) { m2 = m1; m1 = e.x; } else if (e.x < m2) m2 = e.x;
                if (e.y < m1) { m2 = m1; m1 = e.y; } else if (e.y < m2) m2 = e.y;
            }
            partials[(size_t)(cb * 2 + n2) * BB + row0 + row] = make_uint2(m1, m2);
        }
    }
    #undef STAGE
}

// merge partials -> candidates -> numpy-fp32 rescore -> idx/hist/loss
__global__ __launch_bounds__(256) void reduce_kernel(
    const float* __restrict__ X, const float* __restrict__ E,
    const float* __restrict__ xsqw, const float* __restrict__ esqw,
    const uint2* __restrict__ partials, int* __restrict__ idxbuf,
    int* __restrict__ hist, double* __restrict__ loss_acc,
    float* __restrict__ out)
{
    __shared__ double lred[256];
    const int row = blockIdx.x * 256 + threadIdx.x;
    unsigned int m = 0xFFFFFFFFu;
    for (int e = 0; e < 64; ++e) m = min(m, partials[(size_t)e * BB + row].x);
    float lim = unpackscore(m) + MARG;
    int cand[NCAND]; int nc = 0;
    for (int e = 0; e < 64; ++e) {
        uint2 p = partials[(size_t)e * BB + row];
        if (unpackscore(p.x) <= lim && nc < NCAND) cand[nc++] = (int)(p.x & 0xFFFu);
        if (unpackscore(p.y) <= lim && nc < NCAND) cand[nc++] = (int)(p.y & 0xFFFu);
    }
    // numpy-fp32 emulated rescore (verbatim, validated R5-R9)
    const float* xr = X + (size_t)row * DD;
    float xs = xsqw[row];
    float bd = 3.0e38f; int bk = 0x7fffffff;
    for (int cidx = 0; cidx < nc; ++cidx) {
        int k = cand[cidx] & (KK - 1);
        const float* er = E + (size_t)k * DD;
        float q1 = 0.f, q2 = 0.f;
        for (int d = 0; d < 384; ++d)   q1 = fmaf(xr[d], er[d], q1);
        for (int d = 384; d < 512; ++d) q2 = fmaf(xr[d], er[d], q2);
        float dot = __fadd_rn(q1, q2);
        float t1  = __fadd_rn(xs, esqw[k]);
        float dnp = __fsub_rn(t1, __fmul_rn(2.0f, dot));
        if (dnp < bd || (dnp == bd && k < bk)) { bd = dnp; bk = k; }
    }
    const float* er = E + (size_t)bk * DD;
    double ls = 0.0;
    for (int d = 0; d < DD; ++d) {
        double df = (double)xr[d] - (double)er[d];
        ls = fma(df, df, ls);
    }
    idxbuf[row] = bk;
    out[IDX_OFF + row] = (float)bk;
    atomicAdd(&hist[bk], 1);
    lred[threadIdx.x] = ls;
    __syncthreads();
    for (int t = 128; t > 0; t >>= 1) {
        if (threadIdx.x < t) lred[threadIdx.x] += lred[threadIdx.x + t];
        __syncthreads();
    }
    if (threadIdx.x == 0) atomicAdd(loss_acc, lred[0]);
}

// one block per row: quantized gather (coalesced) + one-hot row
__global__ __launch_bounds__(256) void encq_kernel(const int* __restrict__ idxbuf,
                                                   const float* __restrict__ E,
                                                   float* __restrict__ out) {
    int row = blockIdx.x;
    int idx = idxbuf[row];
    ((float2*)out)[(size_t)row * 256 + threadIdx.x] =
        ((const float2*)E)[(size_t)idx * 256 + threadIdx.x];
    float2* erow = (float2*)(out + ENC_OFF) + (size_t)row * (KK / 2);
    int half = idx >> 1;
    float2 one;
    if (idx & 1) { one.x = 0.f; one.y = 1.f; } else { one.x = 1.f; one.y = 0.f; }
    float2 z; z.x = 0.f; z.y = 0.f;
    for (int c = threadIdx.x; c < KK / 2; c += 256)
        erow[c] = (c == half) ? one : z;
}

__global__ __launch_bounds__(256) void fin_kernel(const int* __restrict__ hist,
                                                  const double* __restrict__ loss_acc,
                                                  float* __restrict__ out) {
    __shared__ double red[256];
    int tid = threadIdx.x;
    double s = 0.0;
    for (int k = tid; k < KK; k += 256) {
        double p = (double)hist[k] * (1.0 / 32768.0);
        s += p * log(p + 1e-10);
    }
    red[tid] = s;
    __syncthreads();
    for (int t = 128; t > 0; t >>= 1) {
        if (tid < t) red[tid] += red[tid + t];
        __syncthreads();
    }
    if (tid == 0) {
        double perp = exp(-red[0]);
        double L = loss_acc[0] * (1.0 / ((double)BB * (double)DD));
        out[LOSS_OFF] = (float)(1.25 * L);
        out[PERP_OFF] = (float)perp;
    }
}

extern "C" void kernel_launch(void* const* d_in, const int* in_sizes, int n_in,
                              void* d_out, int out_size, void* d_ws, size_t ws_size,
                              hipStream_t stream) {
    const float* X; const float* E;
    if (in_sizes[0] == BB * DD) { X = (const float*)d_in[0]; E = (const float*)d_in[1]; }
    else                        { X = (const float*)d_in[1]; E = (const float*)d_in[0]; }
    float* out = (float*)d_out;

    float* xsq = (float*)((char*)d_ws + WSB_XSQ);
    float* esq = (float*)((char*)d_ws + WSB_ESQ);
    int* idxbuf = (int*)((char*)d_ws + WSB_IDX);
    int* hist   = (int*)((char*)d_ws + WSB_HIST);
    double* loss_acc = (double*)((char*)d_ws + WSB_LOSS);
    unsigned short* Ebf2 = (unsigned short*)((char*)d_ws + WSB_EBF2);
    unsigned short* Xbf  = (unsigned short*)((char*)d_ws + WSB_XBF);
    uint2* partials = (uint2*)((char*)d_ws + WSB_PART);

    hipLaunchKernelGGL(init_kernel, dim3(16), dim3(256), 0, stream, hist, loss_acc);
    hipLaunchKernelGGL(npsum_kernel, dim3((BB + KK) / 4), dim3(256), 0, stream,
                       X, E, xsq, esq);
    hipLaunchKernelGGL(pack_kernel, dim3(1024), dim3(256), 0, stream, E, Ebf2);
    hipLaunchKernelGGL(pack_kernel, dim3(8192), dim3(256), 0, stream, X, Xbf);
    hipLaunchKernelGGL(gemm_screen, dim3(8192), dim3(256), 0, stream,
                       Xbf, Ebf2, esq, partials);
    hipLaunchKernelGGL(reduce_kernel, dim3(BB / 256), dim3(256), 0, stream,
                       X, E, xsq, esq, partials, idxbuf, hist, loss_acc, out);
    hipLaunchKernelGGL(encq_kernel, dim3(BB), dim3(256), 0, stream, idxbuf, E, out);
    hipLaunchKernelGGL(fin_kernel, dim3(1), dim3(256), 0, stream, hist, loss_acc, out);
}